// Round 11
// baseline (231.798 us; speedup 1.0000x reference)
//
#include <hip/hip_runtime.h>
#include <hip/hip_bf16.h>

// GATPredictor: x(8,12,1500) f32 -> 2-layer LSTM(hid64) per (b,n) sequence ->
// 2x GAT(4 heads x 16) over N=1500 graph -> linear head (3) -> (B,3,N) f32.
// LSTM: merged-phase MFMA, SEQB=16 (750 blocks, ~3/CU for phase overlap),
// in-register f32->bf16 weight conversion; adjacency-bitmask generation rides
// in the same launch (blocks 750..1031). gat_prep: MFMA, in-register W cvt.
// gat_agg: flash-style MFMA; final call fuses the linear head. 5 dispatches.

#define BN 12000
#define NNODE 1500
#define NB 8
#define TT 12
#define NPAD 1536   // padded j extent for hpT/esT/edT rows
#define LOG2E 1.44269504f

typedef __bf16 bf16x8 __attribute__((ext_vector_type(8)));
typedef __bf16 bf16x4 __attribute__((ext_vector_type(4)));
typedef float  f32x4  __attribute__((ext_vector_type(4)));

// fast activations: v_rcp_f32 (~1 ulp). exp overflow -> inf -> rcp -> 0 gives
// the correct saturation limit, so no branches needed.
__device__ __forceinline__ float rcpf(float v) { return __builtin_amdgcn_rcpf(v); }
__device__ __forceinline__ float exp2f_(float v) { return __builtin_amdgcn_exp2f(v); }
__device__ __forceinline__ float sigf(float v) { return rcpf(1.f + __expf(-v)); }
__device__ __forceinline__ float tanhf_(float v) {
    return fmaf(2.f, rcpf(1.f + __expf(-2.f * v)), -1.f);
}

// load 8 consecutive f32 and convert to a bf16x8 MFMA fragment
__device__ __forceinline__ bf16x8 ldcvt(const float* __restrict__ p) {
    f32x4 a = *(const f32x4*)p;
    f32x4 b = *(const f32x4*)(p + 4);
    bf16x8 r;
    #pragma unroll
    for (int i = 0; i < 4; ++i) { r[i] = (__bf16)a[i]; r[4 + i] = (__bf16)b[i]; }
    return r;
}

// ---------------------------------------------------------------------------
// LSTM (blocks 0..749, 16 seqs each) + adjacency bitmask (blocks 750..1031).
// LSTM: wave w owns all 4 gates of dims 8w..8w+7 (tileA = i|f, tileB = g|o);
// one MFMA phase computes G1(t) and G0(t+1); gates via shfl_xor(8); c in regs;
// h in LDS bf16. 2 barriers/step. Weights cvt f32->bf16 in-register (L2-hot).
// Mask: mask[i][w] bits j in [w*32,w*32+32); 1504 x 48 words.
// ---------------------------------------------------------------------------
__global__ __launch_bounds__(512, 1) void lstm_mask(
    const float* __restrict__ x,
    const float* __restrict__ Wih0, const float* __restrict__ Whh0,
    const float* __restrict__ bih0, const float* __restrict__ bhh0,
    const float* __restrict__ Wih1, const float* __restrict__ Whh1,
    const float* __restrict__ bih1, const float* __restrict__ bhh1,
    const int* __restrict__ adj, unsigned int* __restrict__ mask,
    float* __restrict__ hfin)
{
    if (blockIdx.x >= 750) {
        // ---- adjacency bitmask: 2256 waves x 16 tasks = 1504 x 24 chunks ----
        int wid  = (blockIdx.x - 750) * 8 + (threadIdx.x >> 6);
        int lane = threadIdx.x & 63;
        #pragma unroll 4
        for (int u = 0; u < 16; ++u) {
            int task = wid * 16 + u;
            int i = task / 24, ch = task - i * 24;
            int j = ch * 64 + lane;
            int a = (i < NNODE && j < NNODE) ? adj[i * NNODE + j] : 0;
            unsigned long long m = __ballot(a > 0);
            if (lane == 0 && i < 1504) *(unsigned long long*)&mask[i * 48 + ch * 2] = m;
        }
        return;
    }

    __shared__ __align__(16) __bf16 h0s[16 * 72];   // 2.25 KB
    __shared__ __align__(16) __bf16 h1s[16 * 72];   // 2.25 KB
    __shared__ __align__(16) float  xls[TT * 16];   // 768 B

    int tid  = threadIdx.x;
    int w    = __builtin_amdgcn_readfirstlane(tid >> 6);
    int lane = tid & 63;
    int l15  = lane & 15;
    int qd   = lane >> 4;
    bool lo  = l15 < 8;
    int dloc = l15 & 7;
    int d    = 8 * w + dloc;

    // zero h1 (576 u32 words > 512 threads -> strided loop, NOT single if!)
    for (int e = tid; e < (16 * 72) / 2; e += 512) ((unsigned int*)h1s)[e] = 0u;
    if (tid < TT * 16) {
        int t = tid >> 4, m = tid & 15;
        int s = blockIdx.x * 16 + m;
        int bb = s / NNODE, nn = s - bb * NNODE;
        xls[tid] = x[bb * (TT * NNODE) + t * NNODE + nn];
    }

    // B-fragment columns: gA = i|f of dim d, gB = g|o of dim d (in-reg cvt)
    int gA = (lo ? 0 : 64) + d;
    int gB = (lo ? 128 : 192) + d;
    bf16x8 B0A[2], B0B[2], B1A[4], B1B[4];
    #pragma unroll
    for (int kt = 0; kt < 2; ++kt) {
        B0A[kt] = ldcvt(&Whh0[gA * 64 + 32 * kt + 8 * qd]);
        B0B[kt] = ldcvt(&Whh0[gB * 64 + 32 * kt + 8 * qd]);
        B1A[kt] = ldcvt(&Wih1[gA * 64 + 32 * kt + 8 * qd]);
        B1B[kt] = ldcvt(&Wih1[gB * 64 + 32 * kt + 8 * qd]);
        B1A[kt + 2] = ldcvt(&Whh1[gA * 64 + 32 * kt + 8 * qd]);
        B1B[kt + 2] = ldcvt(&Whh1[gB * 64 + 32 * kt + 8 * qd]);
    }
    float b0A = bih0[gA] + bhh0[gA], b0B = bih0[gB] + bhh0[gB];
    float b1A = bih1[gA] + bhh1[gA], b1B = bih1[gB] + bhh1[gB];
    float w0A = Wih0[gA], w0B = Wih0[gB];

    float pwi = Wih0[d],       pbi = bih0[d]       + bhh0[d];
    float pwg = Wih0[128 + d], pbg = bih0[128 + d] + bhh0[128 + d];
    float pwo = Wih0[192 + d], pbo = bih0[192 + d] + bhh0[192 + d];

    float c0[2], c1[2];
    c0[0] = c0[1] = c1[0] = c1[1] = 0.f;

    __syncthreads();   // xls + h1s ready

    // ---- prologue: h0(0) from x0 only (h_prev = 0), pure VALU ----
    #pragma unroll
    for (int rl = 0; rl < 2; ++rl) {
        int rr = lo ? rl : 2 + rl;
        int m = 4 * qd + rr;
        float xv = xls[m];
        float gi = fmaf(pwi, xv, pbi);
        float gg = fmaf(pwg, xv, pbg);
        float go = fmaf(pwo, xv, pbo);
        float c = sigf(gi) * tanhf_(gg);
        c0[rl] = c;
        h0s[m * 72 + d] = (__bf16)(sigf(go) * tanhf_(c));
    }
    __syncthreads();

    for (int t = 0; t < TT; ++t) {
        bool last = (t == TT - 1);
        // ===== phase 1: all MFMAs (G1(t), and G0(t+1) unless last) =====
        bf16x8 a0[2], a1[2];
        #pragma unroll
        for (int kt = 0; kt < 2; ++kt) {
            a0[kt] = *(bf16x8*)&h0s[l15 * 72 + 32 * kt + 8 * qd];
            a1[kt] = *(bf16x8*)&h1s[l15 * 72 + 32 * kt + 8 * qd];
        }
        f32x4 AA1, AB1, AA0, AB0;
        #pragma unroll
        for (int r = 0; r < 4; ++r) { AA1[r] = b1A; AB1[r] = b1B; }
        if (!last) {
            f32x4 xv = *(f32x4*)&xls[(t + 1) * 16 + 4 * qd];
            #pragma unroll
            for (int r = 0; r < 4; ++r) {
                AA0[r] = fmaf(w0A, xv[r], b0A);
                AB0[r] = fmaf(w0B, xv[r], b0B);
            }
        }
        #pragma unroll
        for (int kt = 0; kt < 2; ++kt) {
            AA1 = __builtin_amdgcn_mfma_f32_16x16x32_bf16(a0[kt], B1A[kt], AA1, 0, 0, 0);
            AB1 = __builtin_amdgcn_mfma_f32_16x16x32_bf16(a0[kt], B1B[kt], AB1, 0, 0, 0);
            AA1 = __builtin_amdgcn_mfma_f32_16x16x32_bf16(a1[kt], B1A[kt + 2], AA1, 0, 0, 0);
            AB1 = __builtin_amdgcn_mfma_f32_16x16x32_bf16(a1[kt], B1B[kt + 2], AB1, 0, 0, 0);
        }
        if (!last) {
            #pragma unroll
            for (int kt = 0; kt < 2; ++kt) {
                AA0 = __builtin_amdgcn_mfma_f32_16x16x32_bf16(a0[kt], B0A[kt], AA0, 0, 0, 0);
                AB0 = __builtin_amdgcn_mfma_f32_16x16x32_bf16(a0[kt], B0B[kt], AB0, 0, 0, 0);
            }
        }
        __syncthreads();   // all h reads of this step done

        // ===== phase 2: gates (partner gates via shfl_xor 8) =====
        {
            float shA0 = __shfl_xor(lo ? AA1[2] : AA1[0], 8);
            float shA1 = __shfl_xor(lo ? AA1[3] : AA1[1], 8);
            float shB0 = __shfl_xor(lo ? AB1[2] : AB1[0], 8);
            float shB1 = __shfl_xor(lo ? AB1[3] : AB1[1], 8);
            #pragma unroll
            for (int rl = 0; rl < 2; ++rl) {
                int rr = lo ? rl : 2 + rl;
                float ownA = AA1[rr], ownB = AB1[rr];
                float shA = rl ? shA1 : shA0, shB = rl ? shB1 : shB0;
                float gi = lo ? ownA : shA;
                float gf = lo ? shA : ownA;
                float gg = lo ? ownB : shB;
                float go = lo ? shB : ownB;
                float c = sigf(gf) * c1[rl] + sigf(gi) * tanhf_(gg);
                c1[rl] = c;
                float hv = sigf(go) * tanhf_(c);
                int m = 4 * qd + rr;
                if (!last) h1s[m * 72 + d] = (__bf16)hv;
                else       hfin[(blockIdx.x * 16 + m) * 64 + d] = hv;
            }
        }
        if (!last) {
            float shA0 = __shfl_xor(lo ? AA0[2] : AA0[0], 8);
            float shA1 = __shfl_xor(lo ? AA0[3] : AA0[1], 8);
            float shB0 = __shfl_xor(lo ? AB0[2] : AB0[0], 8);
            float shB1 = __shfl_xor(lo ? AB0[3] : AB0[1], 8);
            #pragma unroll
            for (int rl = 0; rl < 2; ++rl) {
                int rr = lo ? rl : 2 + rl;
                float ownA = AA0[rr], ownB = AB0[rr];
                float shA = rl ? shA1 : shA0, shB = rl ? shB1 : shB0;
                float gi = lo ? ownA : shA;
                float gf = lo ? shA : ownA;
                float gg = lo ? ownB : shB;
                float go = lo ? shB : ownB;
                float c = sigf(gf) * c0[rl] + sigf(gi) * tanhf_(gg);
                c0[rl] = c;
                int m = 4 * qd + rr;
                h0s[m * 72 + d] = (__bf16)(sigf(go) * tanhf_(c));
            }
        }
        __syncthreads();   // new h visible before next phase 1
    }
}

// ---------------------------------------------------------------------------
// GAT projection, MFMA: hpT[b*64+d][n] = (h @ W.T)^T  (bf16), plus
// esT/edT[b*4+h][n] pre-scaled by log2(e). Block = 64 nodes, 4 waves x 16.
// A = W rows (f32 -> bf16 in-register), B = h fragments.
// C[col=node][row=dim] staged to LDS [64 dim][72] -> coalesced row stores.
// ---------------------------------------------------------------------------
__global__ __launch_bounds__(256) void gat_prep(
    const float* __restrict__ hin, const float* __restrict__ W,
    const float* __restrict__ asrc, const float* __restrict__ adst,
    __bf16* __restrict__ hpT, float* __restrict__ esT, float* __restrict__ edT)
{
    __shared__ __align__(16) __bf16 hp_t[64 * 72];   // [dim][node] 9 KB
    __shared__ float avs[128];

    int tid  = threadIdx.x;
    int wv   = tid >> 6;
    int lane = tid & 63;
    int l15  = lane & 15;
    int qd   = lane >> 4;

    if (tid < 64)       avs[tid] = asrc[tid] * LOG2E;
    else if (tid < 128) avs[tid] = adst[tid - 64] * LOG2E;

    int s0 = blockIdx.x * 64;
    int sn = s0 + wv * 16 + l15;
    int snc = min(sn, BN - 1);

    // B-fragments: B[n=l15][k=qd*8+j], two K-halves
    bf16x8 Bf[2];
    #pragma unroll
    for (int kt = 0; kt < 2; ++kt) Bf[kt] = ldcvt(&hin[snc * 64 + kt * 32 + qd * 8]);
    __syncthreads();   // avs ready

    f32x4 acc[4];
    #pragma unroll
    for (int mt = 0; mt < 4; ++mt) {
        int dd = mt * 16 + l15;
        bf16x8 A0 = ldcvt(&W[dd * 64 + qd * 8]);
        bf16x8 A1 = ldcvt(&W[dd * 64 + 32 + qd * 8]);
        f32x4 a = {0.f, 0.f, 0.f, 0.f};
        a = __builtin_amdgcn_mfma_f32_16x16x32_bf16(A0, Bf[0], a, 0, 0, 0);
        a = __builtin_amdgcn_mfma_f32_16x16x32_bf16(A1, Bf[1], a, 0, 0, 0);
        acc[mt] = a;
    }

    // es/ed per head (head == mt) + stage hp into LDS transposed
    #pragma unroll
    for (int mt = 0; mt < 4; ++mt) {
        float ts = 0.f, td = 0.f;
        #pragma unroll
        for (int r = 0; r < 4; ++r) {
            int dd = mt * 16 + qd * 4 + r;
            ts = fmaf(acc[mt][r], avs[dd], ts);
            td = fmaf(acc[mt][r], avs[64 + dd], td);
            hp_t[dd * 72 + wv * 16 + l15] = (__bf16)acc[mt][r];
        }
        ts += __shfl_xor(ts, 16); ts += __shfl_xor(ts, 32);
        td += __shfl_xor(td, 16); td += __shfl_xor(td, 32);
        if (qd == 0 && sn < BN) {
            int b = sn / NNODE, n = sn - b * NNODE;
            esT[(b * 4 + mt) * NPAD + n] = ts;
            edT[(b * 4 + mt) * NPAD + n] = td;
        }
    }
    __syncthreads();

    // write-out: rows of 64 nodes, coalesced (fast path when block is in one b)
    int dim = tid >> 2, seg = tid & 3;
    int b0 = s0 / NNODE, b1 = (s0 + 63) / NNODE;
    if (b0 == b1 && s0 + 63 < BN) {
        int n0 = s0 - b0 * NNODE;   // multiple of 4 -> 8-B aligned stores
        bf16x4 v0 = *(bf16x4*)&hp_t[dim * 72 + seg * 16];
        bf16x4 v1 = *(bf16x4*)&hp_t[dim * 72 + seg * 16 + 4];
        bf16x4 v2 = *(bf16x4*)&hp_t[dim * 72 + seg * 16 + 8];
        bf16x4 v3 = *(bf16x4*)&hp_t[dim * 72 + seg * 16 + 12];
        __bf16* dst = &hpT[((b0 << 6) + dim) * NPAD + n0 + seg * 16];
        *(bf16x4*)(dst)      = v0;
        *(bf16x4*)(dst + 4)  = v1;
        *(bf16x4*)(dst + 8)  = v2;
        *(bf16x4*)(dst + 12) = v3;
    } else {
        #pragma unroll
        for (int u = 0; u < 16; ++u) {
            int ss = s0 + seg * 16 + u;
            if (ss < BN) {
                int b = ss / NNODE, n = ss - b * NNODE;
                hpT[((b << 6) + dim) * NPAD + n] = hp_t[dim * 72 + seg * 16 + u];
            }
        }
    }
}

// ---------------------------------------------------------------------------
// GAT aggregation, flash-style MFMA. esT/edT pre-scaled by log2(e) so
// p = exp2(leaky(es'+ed')). final=1: fuse the 3-wide output head.
// ---------------------------------------------------------------------------
__global__ __launch_bounds__(512) void gat_agg(
    const __bf16* __restrict__ hpT, const float* __restrict__ esT,
    const float* __restrict__ edT, const unsigned int* __restrict__ mask,
    float* __restrict__ hout, const float* __restrict__ oW,
    const float* __restrict__ ob, float* __restrict__ outp, int final)
{
    __shared__ float Ss[8][16];
    __shared__ float hbuf[32 * 72];   // 9 KB (final path)
    __shared__ float oWs[192];
    __shared__ float obs[3];

    int tid  = threadIdx.x;
    int wv   = tid >> 6;
    int lane = tid & 63;
    int l15  = lane & 15;
    int qd   = lane >> 4;
    int hh   = wv & 3;
    int ig   = wv >> 2;
    int b    = blockIdx.x / 47;
    int i0   = (blockIdx.x % 47) * 32;
    int it   = i0 + ig * 16;

    if (final) {
        if (tid < 192) oWs[tid] = oW[tid];
        if (tid < 3)   obs[tid] = ob[tid];
    }

    const __bf16* Brow = hpT + (((b << 6) + (hh << 4) + l15) * NPAD);
    const float* edrow = edT + (b * 4 + hh) * NPAD;
    const unsigned int* mrow = mask + (it + l15) * 48;
    float esv = esT[(b * 4 + hh) * NPAD + it + l15];

    f32x4 acc = {0.f, 0.f, 0.f, 0.f};
    float S = 0.f;

    for (int jt = 0; jt < 12; ++jt) {
        uint4 mw = *(const uint4*)&mrow[jt * 4];
        #pragma unroll
        for (int kt = 0; kt < 4; ++kt) {
            int jk = jt * 128 + kt * 32 + qd * 8;
            float4 e0 = *(const float4*)&edrow[jk];
            float4 e1 = *(const float4*)&edrow[jk + 4];
            unsigned int mb = ((&mw.x)[kt] >> (qd * 8)) & 0xffu;
            float ej[8] = {e0.x, e0.y, e0.z, e0.w, e1.x, e1.y, e1.z, e1.w};
            bf16x8 A;
            #pragma unroll
            for (int jj = 0; jj < 8; ++jj) {
                float e = esv + ej[jj];
                e = fmaxf(e, 0.2f * e);
                float p = ((mb >> jj) & 1u) ? exp2f_(e) : 0.f;
                S += p;
                A[jj] = (__bf16)p;
            }
            bf16x8 B = *(const bf16x8*)&Brow[jk];
            acc = __builtin_amdgcn_mfma_f32_16x16x32_bf16(A, B, acc, 0, 0, 0);
        }
    }

    S += __shfl_xor(S, 16);
    S += __shfl_xor(S, 32);
    if (qd == 0) Ss[wv][l15] = S;
    __syncthreads();

    if (!final) {
        #pragma unroll
        for (int r = 0; r < 4; ++r) {
            int i = it + qd * 4 + r;
            if (i < NNODE) {
                float rs = rcpf(Ss[wv][qd * 4 + r]);
                hout[((b * NNODE + i) << 6) + (hh << 4) + l15] = fmaxf(acc[r] * rs, 0.f);
            }
        }
    } else {
        #pragma unroll
        for (int r = 0; r < 4; ++r) {
            float rs = rcpf(Ss[wv][qd * 4 + r]);
            hbuf[(ig * 16 + qd * 4 + r) * 72 + (hh << 4) + l15] = fmaxf(acc[r] * rs, 0.f);
        }
        __syncthreads();
        if (tid < 384) {
            int idx = tid >> 2, ks = tid & 3;
            int nl = idx & 31, o = idx >> 5;
            if (i0 + nl < NNODE) {
                const float* hb = &hbuf[nl * 72 + ks * 16];
                float a = 0.f;
                #pragma unroll
                for (int kk = 0; kk < 16; ++kk)
                    a = fmaf(hb[kk], oWs[o * 64 + ks * 16 + kk], a);
                a += __shfl_xor(a, 1);
                a += __shfl_xor(a, 2);
                if (ks == 0)
                    outp[(long)b * 3 * NNODE + o * NNODE + i0 + nl] = a + obs[o];
            }
        }
    }
}

// ---------------------------------------------------------------------------
extern "C" void kernel_launch(void* const* d_in, const int* in_sizes, int n_in,
                              void* d_out, int out_size, void* d_ws, size_t ws_size,
                              hipStream_t stream) {
    const float* x    = (const float*)d_in[0];
    const int*   adj  = (const int*)d_in[1];
    const float* Wih0 = (const float*)d_in[2];
    const float* Whh0 = (const float*)d_in[3];
    const float* bih0 = (const float*)d_in[4];
    const float* bhh0 = (const float*)d_in[5];
    const float* Wih1 = (const float*)d_in[6];
    const float* Whh1 = (const float*)d_in[7];
    const float* bih1 = (const float*)d_in[8];
    const float* bhh1 = (const float*)d_in[9];
    const float* g0W  = (const float*)d_in[10];
    const float* g0s  = (const float*)d_in[11];
    const float* g0d  = (const float*)d_in[12];
    const float* g1W  = (const float*)d_in[13];
    const float* g1s  = (const float*)d_in[14];
    const float* g1d  = (const float*)d_in[15];
    const float* oW   = (const float*)d_in[16];
    const float* ob   = (const float*)d_in[17];

    float* ws = (float*)d_ws;
    float*        bufh  = ws;                              // 768000 f32
    float*        esT   = ws + 768000;                     // 49152
    float*        edT   = ws + 817152;                     // 49152
    __bf16*       hpT   = (__bf16*)(ws + 866304);          // 512*1536 bf16
    unsigned int* maskp = (unsigned int*)(ws + 1259520);   // 72192 u32

    lstm_mask<<<1032, 512, 0, stream>>>(x, Wih0, Whh0, bih0, bhh0,
                                        Wih1, Whh1, bih1, bhh1,
                                        adj, maskp, bufh);
    gat_prep<<<188, 256, 0, stream>>>(bufh, g0W, g0s, g0d, hpT, esT, edT);
    gat_agg<<<376, 512, 0, stream>>>(hpT, esT, edT, maskp, bufh,
                                     oW, ob, (float*)d_out, 0);
    gat_prep<<<188, 256, 0, stream>>>(bufh, g1W, g1s, g1d, hpT, esT, edT);
    gat_agg<<<376, 512, 0, stream>>>(hpT, esT, edT, maskp, bufh,
                                     oW, ob, (float*)d_out, 1);
}

// Round 12
// 219.517 us; speedup vs baseline: 1.0559x; 1.0559x over previous
//
#include <hip/hip_runtime.h>
#include <hip/hip_bf16.h>

// GATPredictor: x(8,12,1500) f32 -> 2-layer LSTM(hid64) per (b,n) sequence ->
// 2x GAT(4 heads x 16) over N=1500 graph -> linear head (3) -> (B,3,N) f32.
// 3 dispatches:
//   A) lstm_mask_prep: LSTM (750 blk x 16 seq, merged-phase MFMA) + adjacency
//      bitmask (blocks 750..1031) + fused GAT0 projection (prep is per-node!)
//   B) gat_mid: flash-MFMA GAT0 aggregation + fused GAT1 projection
//   C) gat_fin: flash-MFMA GAT1 aggregation + fused linear head -> d_out
// prep fusions are legal because hp/es/ed depend only on the block's own
// nodes; only the aggregations need all-nodes visibility (dispatch boundary).

#define BN 12000
#define NNODE 1500
#define NB 8
#define TT 12
#define NPAD 1536   // padded j extent for hpT/esT/edT rows
#define LOG2E 1.44269504f

typedef __bf16 bf16x8 __attribute__((ext_vector_type(8)));
typedef __bf16 bf16x4 __attribute__((ext_vector_type(4)));
typedef float  f32x4  __attribute__((ext_vector_type(4)));

__device__ __forceinline__ float rcpf(float v) { return __builtin_amdgcn_rcpf(v); }
__device__ __forceinline__ float exp2f_(float v) { return __builtin_amdgcn_exp2f(v); }
__device__ __forceinline__ float sigf(float v) { return rcpf(1.f + __expf(-v)); }
__device__ __forceinline__ float tanhf_(float v) {
    return fmaf(2.f, rcpf(1.f + __expf(-2.f * v)), -1.f);
}

// load 8 consecutive f32 (global or LDS) -> bf16x8 MFMA fragment
__device__ __forceinline__ bf16x8 ldcvt(const float* p) {
    f32x4 a = *(const f32x4*)p;
    f32x4 b = *(const f32x4*)(p + 4);
    bf16x8 r;
    #pragma unroll
    for (int i = 0; i < 4; ++i) { r[i] = (__bf16)a[i]; r[4 + i] = (__bf16)b[i]; }
    return r;
}

// ---------------------------------------------------------------------------
// Kernel A: LSTM (blocks 0..749, 16 seqs) + mask gen (750..1031) + prep0.
// ---------------------------------------------------------------------------
__global__ __launch_bounds__(512, 1) void lstm_mask_prep(
    const float* __restrict__ x,
    const float* __restrict__ Wih0, const float* __restrict__ Whh0,
    const float* __restrict__ bih0, const float* __restrict__ bhh0,
    const float* __restrict__ Wih1, const float* __restrict__ Whh1,
    const float* __restrict__ bih1, const float* __restrict__ bhh1,
    const int* __restrict__ adj, unsigned int* __restrict__ mask,
    const float* __restrict__ gW, const float* __restrict__ asrc,
    const float* __restrict__ adst,
    __bf16* __restrict__ hpT, float* __restrict__ esT, float* __restrict__ edT)
{
    if (blockIdx.x >= 750) {
        // ---- adjacency bitmask: 1504 rows x 24 chunks of 64 ----
        int wid  = (blockIdx.x - 750) * 8 + (threadIdx.x >> 6);
        int lane = threadIdx.x & 63;
        #pragma unroll 4
        for (int u = 0; u < 16; ++u) {
            int task = wid * 16 + u;
            int i = task / 24, ch = task - i * 24;
            int j = ch * 64 + lane;
            int a = (i < NNODE && j < NNODE) ? adj[i * NNODE + j] : 0;
            unsigned long long m = __ballot(a > 0);
            if (lane == 0 && i < 1504) *(unsigned long long*)&mask[i * 48 + ch * 2] = m;
        }
        return;
    }

    __shared__ __align__(16) __bf16 h0s[16 * 72];   // 2.25 KB
    __shared__ __align__(16) __bf16 h1s[16 * 72];   // 2.25 KB
    __shared__ __align__(16) float  xls[TT * 16];   // 768 B
    __shared__ float avs[128];
    __shared__ __align__(16) __bf16 hp_t[64 * 24];  // [dim][node] 3 KB

    int tid  = threadIdx.x;
    int w    = __builtin_amdgcn_readfirstlane(tid >> 6);
    int lane = tid & 63;
    int l15  = lane & 15;
    int qd   = lane >> 4;
    bool lo  = l15 < 8;
    int dloc = l15 & 7;
    int d    = 8 * w + dloc;

    // zero h1 (576 u32 words > 512 threads -> strided loop)
    for (int e = tid; e < (16 * 72) / 2; e += 512) ((unsigned int*)h1s)[e] = 0u;
    if (tid < TT * 16) {
        int t = tid >> 4, m = tid & 15;
        int s = blockIdx.x * 16 + m;
        int bb = s / NNODE, nn = s - bb * NNODE;
        xls[tid] = x[bb * (TT * NNODE) + t * NNODE + nn];
    }
    if (tid < 64)       avs[tid] = asrc[tid] * LOG2E;
    else if (tid < 128) avs[tid] = adst[tid - 64] * LOG2E;

    // B-fragment columns: gA = i|f of dim d, gB = g|o of dim d (in-reg cvt)
    int gA = (lo ? 0 : 64) + d;
    int gB = (lo ? 128 : 192) + d;
    bf16x8 B0A[2], B0B[2], B1A[4], B1B[4];
    #pragma unroll
    for (int kt = 0; kt < 2; ++kt) {
        B0A[kt] = ldcvt(&Whh0[gA * 64 + 32 * kt + 8 * qd]);
        B0B[kt] = ldcvt(&Whh0[gB * 64 + 32 * kt + 8 * qd]);
        B1A[kt] = ldcvt(&Wih1[gA * 64 + 32 * kt + 8 * qd]);
        B1B[kt] = ldcvt(&Wih1[gB * 64 + 32 * kt + 8 * qd]);
        B1A[kt + 2] = ldcvt(&Whh1[gA * 64 + 32 * kt + 8 * qd]);
        B1B[kt + 2] = ldcvt(&Whh1[gB * 64 + 32 * kt + 8 * qd]);
    }
    float b0A = bih0[gA] + bhh0[gA], b0B = bih0[gB] + bhh0[gB];
    float b1A = bih1[gA] + bhh1[gA], b1B = bih1[gB] + bhh1[gB];
    float w0A = Wih0[gA], w0B = Wih0[gB];

    float pwi = Wih0[d],       pbi = bih0[d]       + bhh0[d];
    float pwg = Wih0[128 + d], pbg = bih0[128 + d] + bhh0[128 + d];
    float pwo = Wih0[192 + d], pbo = bih0[192 + d] + bhh0[192 + d];

    float c0[2], c1[2];
    c0[0] = c0[1] = c1[0] = c1[1] = 0.f;

    __syncthreads();   // xls + h1s ready

    // prologue: h0(0) from x0 only (h_prev = 0)
    #pragma unroll
    for (int rl = 0; rl < 2; ++rl) {
        int rr = lo ? rl : 2 + rl;
        int m = 4 * qd + rr;
        float xv = xls[m];
        float gi = fmaf(pwi, xv, pbi);
        float gg = fmaf(pwg, xv, pbg);
        float go = fmaf(pwo, xv, pbo);
        float c = sigf(gi) * tanhf_(gg);
        c0[rl] = c;
        h0s[m * 72 + d] = (__bf16)(sigf(go) * tanhf_(c));
    }
    __syncthreads();

    for (int t = 0; t < TT; ++t) {
        bool last = (t == TT - 1);
        // phase 1: MFMAs (G1(t), and G0(t+1) unless last)
        bf16x8 a0[2], a1[2];
        #pragma unroll
        for (int kt = 0; kt < 2; ++kt) {
            a0[kt] = *(bf16x8*)&h0s[l15 * 72 + 32 * kt + 8 * qd];
            a1[kt] = *(bf16x8*)&h1s[l15 * 72 + 32 * kt + 8 * qd];
        }
        f32x4 AA1, AB1, AA0, AB0;
        #pragma unroll
        for (int r = 0; r < 4; ++r) { AA1[r] = b1A; AB1[r] = b1B; }
        if (!last) {
            f32x4 xv = *(f32x4*)&xls[(t + 1) * 16 + 4 * qd];
            #pragma unroll
            for (int r = 0; r < 4; ++r) {
                AA0[r] = fmaf(w0A, xv[r], b0A);
                AB0[r] = fmaf(w0B, xv[r], b0B);
            }
        }
        #pragma unroll
        for (int kt = 0; kt < 2; ++kt) {
            AA1 = __builtin_amdgcn_mfma_f32_16x16x32_bf16(a0[kt], B1A[kt], AA1, 0, 0, 0);
            AB1 = __builtin_amdgcn_mfma_f32_16x16x32_bf16(a0[kt], B1B[kt], AB1, 0, 0, 0);
            AA1 = __builtin_amdgcn_mfma_f32_16x16x32_bf16(a1[kt], B1A[kt + 2], AA1, 0, 0, 0);
            AB1 = __builtin_amdgcn_mfma_f32_16x16x32_bf16(a1[kt], B1B[kt + 2], AB1, 0, 0, 0);
        }
        if (!last) {
            #pragma unroll
            for (int kt = 0; kt < 2; ++kt) {
                AA0 = __builtin_amdgcn_mfma_f32_16x16x32_bf16(a0[kt], B0A[kt], AA0, 0, 0, 0);
                AB0 = __builtin_amdgcn_mfma_f32_16x16x32_bf16(a0[kt], B0B[kt], AB0, 0, 0, 0);
            }
        }
        __syncthreads();

        // phase 2: gates
        {
            float shA0 = __shfl_xor(lo ? AA1[2] : AA1[0], 8);
            float shA1 = __shfl_xor(lo ? AA1[3] : AA1[1], 8);
            float shB0 = __shfl_xor(lo ? AB1[2] : AB1[0], 8);
            float shB1 = __shfl_xor(lo ? AB1[3] : AB1[1], 8);
            #pragma unroll
            for (int rl = 0; rl < 2; ++rl) {
                int rr = lo ? rl : 2 + rl;
                float ownA = AA1[rr], ownB = AB1[rr];
                float shA = rl ? shA1 : shA0, shB = rl ? shB1 : shB0;
                float gi = lo ? ownA : shA;
                float gf = lo ? shA : ownA;
                float gg = lo ? ownB : shB;
                float go = lo ? shB : ownB;
                float c = sigf(gf) * c1[rl] + sigf(gi) * tanhf_(gg);
                c1[rl] = c;
                float hv = sigf(go) * tanhf_(c);
                int m = 4 * qd + rr;
                h1s[m * 72 + d] = (__bf16)hv;   // final h1 stays in LDS for prep0
            }
        }
        if (!last) {
            float shA0 = __shfl_xor(lo ? AA0[2] : AA0[0], 8);
            float shA1 = __shfl_xor(lo ? AA0[3] : AA0[1], 8);
            float shB0 = __shfl_xor(lo ? AB0[2] : AB0[0], 8);
            float shB1 = __shfl_xor(lo ? AB0[3] : AB0[1], 8);
            #pragma unroll
            for (int rl = 0; rl < 2; ++rl) {
                int rr = lo ? rl : 2 + rl;
                float ownA = AA0[rr], ownB = AB0[rr];
                float shA = rl ? shA1 : shA0, shB = rl ? shB1 : shB0;
                float gi = lo ? ownA : shA;
                float gf = lo ? shA : ownA;
                float gg = lo ? ownB : shB;
                float go = lo ? shB : ownB;
                float c = sigf(gf) * c0[rl] + sigf(gi) * tanhf_(gg);
                c0[rl] = c;
                int m = 4 * qd + rr;
                h0s[m * 72 + d] = (__bf16)(sigf(go) * tanhf_(c));
            }
        }
        __syncthreads();
    }

    // ---- fused prep0: hp = h1 @ W0^T for this block's 16 nodes ----
    int s0 = blockIdx.x * 16;
    if (w < 4) {                       // wave w = dim-tile mt = head mt
        int mt = w;
        bf16x8 Bf0 = *(bf16x8*)&h1s[l15 * 72 + 8 * qd];
        bf16x8 Bf1 = *(bf16x8*)&h1s[l15 * 72 + 32 + 8 * qd];
        bf16x8 A0 = ldcvt(&gW[(mt * 16 + l15) * 64 + 8 * qd]);
        bf16x8 A1 = ldcvt(&gW[(mt * 16 + l15) * 64 + 32 + 8 * qd]);
        f32x4 a = {0.f, 0.f, 0.f, 0.f};
        a = __builtin_amdgcn_mfma_f32_16x16x32_bf16(A0, Bf0, a, 0, 0, 0);
        a = __builtin_amdgcn_mfma_f32_16x16x32_bf16(A1, Bf1, a, 0, 0, 0);
        float ts = 0.f, td = 0.f;
        #pragma unroll
        for (int r = 0; r < 4; ++r) {
            int dd = mt * 16 + qd * 4 + r;
            ts = fmaf(a[r], avs[dd], ts);
            td = fmaf(a[r], avs[64 + dd], td);
            hp_t[dd * 24 + l15] = (__bf16)a[r];
        }
        ts += __shfl_xor(ts, 16); ts += __shfl_xor(ts, 32);
        td += __shfl_xor(td, 16); td += __shfl_xor(td, 32);
        if (qd == 0) {
            int s = s0 + l15, b = s / NNODE, n = s - b * NNODE;
            esT[(b * 4 + mt) * NPAD + n] = ts;
            edT[(b * 4 + mt) * NPAD + n] = td;
        }
    }
    __syncthreads();
    if (tid < 256) {
        int dim = tid >> 2, seg = tid & 3;
        int b0 = s0 / NNODE, b1 = (s0 + 15) / NNODE;
        if (b0 == b1) {
            int n0 = s0 - b0 * NNODE;   // multiple of 4 -> 8-B aligned
            bf16x4 v = *(bf16x4*)&hp_t[dim * 24 + seg * 4];
            *(bf16x4*)&hpT[((b0 << 6) + dim) * NPAD + n0 + seg * 4] = v;
        } else {
            #pragma unroll
            for (int u = 0; u < 4; ++u) {
                int ss = s0 + seg * 4 + u;
                int b = ss / NNODE, n = ss - b * NNODE;
                hpT[((b << 6) + dim) * NPAD + n] = hp_t[dim * 24 + seg * 4 + u];
            }
        }
    }
}

// ---------------------------------------------------------------------------
// Kernel B: GAT0 aggregation (flash-MFMA) + fused GAT1 projection.
// Block = 32 nodes of one batch b; 8 waves = (head hh) x (node-half ig).
// Invalid nodes (i>=1500): mask rows are zero -> S=0 -> rs=inf ->
// fmaxf(0*inf=nan, 0)=0 -> hbuf=0 -> prep1 emits clean zeros.
// ---------------------------------------------------------------------------
__global__ __launch_bounds__(512, 1) void gat_mid(
    const __bf16* __restrict__ hpT, const float* __restrict__ esT,
    const float* __restrict__ edT, const unsigned int* __restrict__ mask,
    const float* __restrict__ gW, const float* __restrict__ asrc,
    const float* __restrict__ adst,
    __bf16* __restrict__ hpT1, float* __restrict__ esT1, float* __restrict__ edT1)
{
    __shared__ float Ss[8][16];
    __shared__ float hbuf[32 * 72];                 // 9 KB: relu(h) [node][dim]
    __shared__ float avs[128];
    __shared__ __align__(16) __bf16 hp1_t[64 * 40]; // 5 KB [dim][node]

    int tid  = threadIdx.x;
    int wv   = tid >> 6;
    int lane = tid & 63;
    int l15  = lane & 15;
    int qd   = lane >> 4;
    int hh   = wv & 3;
    int ig   = wv >> 2;
    int b    = blockIdx.x / 47;
    int i0   = (blockIdx.x % 47) * 32;
    int it   = i0 + ig * 16;

    if (tid < 64)       avs[tid] = asrc[tid] * LOG2E;
    else if (tid < 128) avs[tid] = adst[tid - 64] * LOG2E;

    const __bf16* Brow = hpT + (((b << 6) + (hh << 4) + l15) * NPAD);
    const float* edrow = edT + (b * 4 + hh) * NPAD;
    const unsigned int* mrow = mask + (it + l15) * 48;
    float esv = esT[(b * 4 + hh) * NPAD + it + l15];

    f32x4 acc = {0.f, 0.f, 0.f, 0.f};
    float S = 0.f;

    for (int jt = 0; jt < 12; ++jt) {
        uint4 mw = *(const uint4*)&mrow[jt * 4];
        #pragma unroll
        for (int kt = 0; kt < 4; ++kt) {
            int jk = jt * 128 + kt * 32 + qd * 8;
            float4 e0 = *(const float4*)&edrow[jk];
            float4 e1 = *(const float4*)&edrow[jk + 4];
            unsigned int mb = ((&mw.x)[kt] >> (qd * 8)) & 0xffu;
            float ej[8] = {e0.x, e0.y, e0.z, e0.w, e1.x, e1.y, e1.z, e1.w};
            bf16x8 A;
            #pragma unroll
            for (int jj = 0; jj < 8; ++jj) {
                float e = esv + ej[jj];
                e = fmaxf(e, 0.2f * e);
                float p = ((mb >> jj) & 1u) ? exp2f_(e) : 0.f;
                S += p;
                A[jj] = (__bf16)p;
            }
            bf16x8 B = *(const bf16x8*)&Brow[jk];
            acc = __builtin_amdgcn_mfma_f32_16x16x32_bf16(A, B, acc, 0, 0, 0);
        }
    }

    S += __shfl_xor(S, 16);
    S += __shfl_xor(S, 32);
    if (qd == 0) Ss[wv][l15] = S;
    __syncthreads();

    #pragma unroll
    for (int r = 0; r < 4; ++r) {
        float rs = rcpf(Ss[wv][qd * 4 + r]);
        hbuf[(ig * 16 + qd * 4 + r) * 72 + (hh << 4) + l15] = fmaxf(acc[r] * rs, 0.f);
    }
    __syncthreads();

    // ---- fused prep1: wave (ig, mt=hh) does node-half ig, dim-tile hh ----
    {
        int mt = hh;
        bf16x8 Bf0 = ldcvt(&hbuf[(ig * 16 + l15) * 72 + 8 * qd]);
        bf16x8 Bf1 = ldcvt(&hbuf[(ig * 16 + l15) * 72 + 32 + 8 * qd]);
        bf16x8 A0 = ldcvt(&gW[(mt * 16 + l15) * 64 + 8 * qd]);
        bf16x8 A1 = ldcvt(&gW[(mt * 16 + l15) * 64 + 32 + 8 * qd]);
        f32x4 a = {0.f, 0.f, 0.f, 0.f};
        a = __builtin_amdgcn_mfma_f32_16x16x32_bf16(A0, Bf0, a, 0, 0, 0);
        a = __builtin_amdgcn_mfma_f32_16x16x32_bf16(A1, Bf1, a, 0, 0, 0);
        float ts = 0.f, td = 0.f;
        #pragma unroll
        for (int r = 0; r < 4; ++r) {
            int dd = mt * 16 + qd * 4 + r;
            ts = fmaf(a[r], avs[dd], ts);
            td = fmaf(a[r], avs[64 + dd], td);
            hp1_t[dd * 40 + ig * 16 + l15] = (__bf16)a[r];
        }
        ts += __shfl_xor(ts, 16); ts += __shfl_xor(ts, 32);
        td += __shfl_xor(td, 16); td += __shfl_xor(td, 32);
        if (qd == 0) {
            int n = i0 + ig * 16 + l15;
            esT1[(b * 4 + mt) * NPAD + n] = ts;
            edT1[(b * 4 + mt) * NPAD + n] = td;
        }
    }
    __syncthreads();
    if (tid < 256) {
        int dim = tid >> 2, seg = tid & 3;   // 32 nodes = 4 segs x 8
        bf16x8 v = *(bf16x8*)&hp1_t[dim * 40 + seg * 8];
        *(bf16x8*)&hpT1[((b << 6) + dim) * NPAD + i0 + seg * 8] = v;
    }
}

// ---------------------------------------------------------------------------
// Kernel C: GAT1 aggregation (flash-MFMA) + fused linear head -> d_out.
// ---------------------------------------------------------------------------
__global__ __launch_bounds__(512, 1) void gat_fin(
    const __bf16* __restrict__ hpT, const float* __restrict__ esT,
    const float* __restrict__ edT, const unsigned int* __restrict__ mask,
    const float* __restrict__ oW, const float* __restrict__ ob,
    float* __restrict__ outp)
{
    __shared__ float Ss[8][16];
    __shared__ float hbuf[32 * 72];
    __shared__ float oWs[192];
    __shared__ float obs[3];

    int tid  = threadIdx.x;
    int wv   = tid >> 6;
    int lane = tid & 63;
    int l15  = lane & 15;
    int qd   = lane >> 4;
    int hh   = wv & 3;
    int ig   = wv >> 2;
    int b    = blockIdx.x / 47;
    int i0   = (blockIdx.x % 47) * 32;
    int it   = i0 + ig * 16;

    if (tid < 192) oWs[tid] = oW[tid];
    if (tid < 3)   obs[tid] = ob[tid];

    const __bf16* Brow = hpT + (((b << 6) + (hh << 4) + l15) * NPAD);
    const float* edrow = edT + (b * 4 + hh) * NPAD;
    const unsigned int* mrow = mask + (it + l15) * 48;
    float esv = esT[(b * 4 + hh) * NPAD + it + l15];

    f32x4 acc = {0.f, 0.f, 0.f, 0.f};
    float S = 0.f;

    for (int jt = 0; jt < 12; ++jt) {
        uint4 mw = *(const uint4*)&mrow[jt * 4];
        #pragma unroll
        for (int kt = 0; kt < 4; ++kt) {
            int jk = jt * 128 + kt * 32 + qd * 8;
            float4 e0 = *(const float4*)&edrow[jk];
            float4 e1 = *(const float4*)&edrow[jk + 4];
            unsigned int mb = ((&mw.x)[kt] >> (qd * 8)) & 0xffu;
            float ej[8] = {e0.x, e0.y, e0.z, e0.w, e1.x, e1.y, e1.z, e1.w};
            bf16x8 A;
            #pragma unroll
            for (int jj = 0; jj < 8; ++jj) {
                float e = esv + ej[jj];
                e = fmaxf(e, 0.2f * e);
                float p = ((mb >> jj) & 1u) ? exp2f_(e) : 0.f;
                S += p;
                A[jj] = (__bf16)p;
            }
            bf16x8 B = *(const bf16x8*)&Brow[jk];
            acc = __builtin_amdgcn_mfma_f32_16x16x32_bf16(A, B, acc, 0, 0, 0);
        }
    }

    S += __shfl_xor(S, 16);
    S += __shfl_xor(S, 32);
    if (qd == 0) Ss[wv][l15] = S;
    __syncthreads();

    #pragma unroll
    for (int r = 0; r < 4; ++r) {
        float rs = rcpf(Ss[wv][qd * 4 + r]);
        hbuf[(ig * 16 + qd * 4 + r) * 72 + (hh << 4) + l15] = fmaxf(acc[r] * rs, 0.f);
    }
    __syncthreads();

    if (tid < 384) {
        int idx = tid >> 2, ks = tid & 3;
        int nl = idx & 31, o = idx >> 5;
        if (i0 + nl < NNODE) {
            const float* hb = &hbuf[nl * 72 + ks * 16];
            float a = 0.f;
            #pragma unroll
            for (int kk = 0; kk < 16; ++kk)
                a = fmaf(hb[kk], oWs[o * 64 + ks * 16 + kk], a);
            a += __shfl_xor(a, 1);
            a += __shfl_xor(a, 2);
            if (ks == 0)
                outp[(long)b * 3 * NNODE + o * NNODE + i0 + nl] = a + obs[o];
        }
    }
}

// ---------------------------------------------------------------------------
extern "C" void kernel_launch(void* const* d_in, const int* in_sizes, int n_in,
                              void* d_out, int out_size, void* d_ws, size_t ws_size,
                              hipStream_t stream) {
    const float* x    = (const float*)d_in[0];
    const int*   adj  = (const int*)d_in[1];
    const float* Wih0 = (const float*)d_in[2];
    const float* Whh0 = (const float*)d_in[3];
    const float* bih0 = (const float*)d_in[4];
    const float* bhh0 = (const float*)d_in[5];
    const float* Wih1 = (const float*)d_in[6];
    const float* Whh1 = (const float*)d_in[7];
    const float* bih1 = (const float*)d_in[8];
    const float* bhh1 = (const float*)d_in[9];
    const float* g0W  = (const float*)d_in[10];
    const float* g0s  = (const float*)d_in[11];
    const float* g0d  = (const float*)d_in[12];
    const float* g1W  = (const float*)d_in[13];
    const float* g1s  = (const float*)d_in[14];
    const float* g1d  = (const float*)d_in[15];
    const float* oW   = (const float*)d_in[16];
    const float* ob   = (const float*)d_in[17];

    float* ws = (float*)d_ws;
    float*        esT0  = ws;                              // 49152
    float*        edT0  = ws + 49152;                      // 49152
    float*        esT1  = ws + 98304;                      // 49152
    float*        edT1  = ws + 147456;                     // 49152
    __bf16*       hpT0  = (__bf16*)(ws + 196608);          // 512*1536 bf16
    __bf16*       hpT1  = (__bf16*)(ws + 589824);          // 512*1536 bf16
    unsigned int* maskp = (unsigned int*)(ws + 983040);    // 72192 u32

    lstm_mask_prep<<<1032, 512, 0, stream>>>(x, Wih0, Whh0, bih0, bhh0,
                                             Wih1, Whh1, bih1, bhh1,
                                             adj, maskp, g0W, g0s, g0d,
                                             hpT0, esT0, edT0);
    gat_mid<<<376, 512, 0, stream>>>(hpT0, esT0, edT0, maskp,
                                     g1W, g1s, g1d, hpT1, esT1, edT1);
    gat_fin<<<376, 512, 0, stream>>>(hpT1, esT1, edT1, maskp,
                                     oW, ob, (float*)d_out);
}

// Round 13
// 190.831 us; speedup vs baseline: 1.2147x; 1.1503x over previous
//
#include <hip/hip_runtime.h>
#include <hip/hip_bf16.h>

// GATPredictor: x(8,12,1500) f32 -> 2-layer LSTM(hid64) per (b,n) sequence ->
// 2x GAT(4 heads x 16) over N=1500 graph -> linear head (3) -> (B,3,N) f32.
// 3 dispatches:
//   A) lstm_mask_prep: LSTM (750 blk x 16 seq, merged-phase MFMA) + adjacency
//      bitmask (blocks 750..1031) + fused GAT0 projection.
//   B) gat_mid: flash-MFMA GAT0 aggregation + fused GAT1 projection.
//   C) gat_fin: flash-MFMA GAT1 aggregation + fused linear head -> d_out.
// Round 13: agg blocks shrunk to 16 i / 4 waves (grid 752: load balance
// 1.47->2.94 blocks/CU) and ed/mask staged in LDS (inner loop: 1 global
// stream instead of 4 -> less L2-latency exposure).

#define BN 12000
#define NNODE 1500
#define NB 8
#define TT 12
#define NPAD 1536   // padded j extent for hpT/esT/edT rows
#define LOG2E 1.44269504f

typedef __bf16 bf16x8 __attribute__((ext_vector_type(8)));
typedef __bf16 bf16x4 __attribute__((ext_vector_type(4)));
typedef float  f32x4  __attribute__((ext_vector_type(4)));

__device__ __forceinline__ float rcpf(float v) { return __builtin_amdgcn_rcpf(v); }
__device__ __forceinline__ float exp2f_(float v) { return __builtin_amdgcn_exp2f(v); }
__device__ __forceinline__ float sigf(float v) { return rcpf(1.f + __expf(-v)); }
__device__ __forceinline__ float tanhf_(float v) {
    return fmaf(2.f, rcpf(1.f + __expf(-2.f * v)), -1.f);
}

// load 8 consecutive f32 (global or LDS) -> bf16x8 MFMA fragment
__device__ __forceinline__ bf16x8 ldcvt(const float* p) {
    f32x4 a = *(const f32x4*)p;
    f32x4 b = *(const f32x4*)(p + 4);
    bf16x8 r;
    #pragma unroll
    for (int i = 0; i < 4; ++i) { r[i] = (__bf16)a[i]; r[4 + i] = (__bf16)b[i]; }
    return r;
}

// ---------------------------------------------------------------------------
// Kernel A: LSTM (blocks 0..749, 16 seqs) + mask gen (750..1031) + prep0.
// (unchanged from round 12 — verified)
// ---------------------------------------------------------------------------
__global__ __launch_bounds__(512, 1) void lstm_mask_prep(
    const float* __restrict__ x,
    const float* __restrict__ Wih0, const float* __restrict__ Whh0,
    const float* __restrict__ bih0, const float* __restrict__ bhh0,
    const float* __restrict__ Wih1, const float* __restrict__ Whh1,
    const float* __restrict__ bih1, const float* __restrict__ bhh1,
    const int* __restrict__ adj, unsigned int* __restrict__ mask,
    const float* __restrict__ gW, const float* __restrict__ asrc,
    const float* __restrict__ adst,
    __bf16* __restrict__ hpT, float* __restrict__ esT, float* __restrict__ edT)
{
    if (blockIdx.x >= 750) {
        int wid  = (blockIdx.x - 750) * 8 + (threadIdx.x >> 6);
        int lane = threadIdx.x & 63;
        #pragma unroll 4
        for (int u = 0; u < 16; ++u) {
            int task = wid * 16 + u;
            int i = task / 24, ch = task - i * 24;
            int j = ch * 64 + lane;
            int a = (i < NNODE && j < NNODE) ? adj[i * NNODE + j] : 0;
            unsigned long long m = __ballot(a > 0);
            if (lane == 0 && i < 1504) *(unsigned long long*)&mask[i * 48 + ch * 2] = m;
        }
        return;
    }

    __shared__ __align__(16) __bf16 h0s[16 * 72];
    __shared__ __align__(16) __bf16 h1s[16 * 72];
    __shared__ __align__(16) float  xls[TT * 16];
    __shared__ float avs[128];
    __shared__ __align__(16) __bf16 hp_t[64 * 24];

    int tid  = threadIdx.x;
    int w    = __builtin_amdgcn_readfirstlane(tid >> 6);
    int lane = tid & 63;
    int l15  = lane & 15;
    int qd   = lane >> 4;
    bool lo  = l15 < 8;
    int dloc = l15 & 7;
    int d    = 8 * w + dloc;

    for (int e = tid; e < (16 * 72) / 2; e += 512) ((unsigned int*)h1s)[e] = 0u;
    if (tid < TT * 16) {
        int t = tid >> 4, m = tid & 15;
        int s = blockIdx.x * 16 + m;
        int bb = s / NNODE, nn = s - bb * NNODE;
        xls[tid] = x[bb * (TT * NNODE) + t * NNODE + nn];
    }
    if (tid < 64)       avs[tid] = asrc[tid] * LOG2E;
    else if (tid < 128) avs[tid] = adst[tid - 64] * LOG2E;

    int gA = (lo ? 0 : 64) + d;
    int gB = (lo ? 128 : 192) + d;
    bf16x8 B0A[2], B0B[2], B1A[4], B1B[4];
    #pragma unroll
    for (int kt = 0; kt < 2; ++kt) {
        B0A[kt] = ldcvt(&Whh0[gA * 64 + 32 * kt + 8 * qd]);
        B0B[kt] = ldcvt(&Whh0[gB * 64 + 32 * kt + 8 * qd]);
        B1A[kt] = ldcvt(&Wih1[gA * 64 + 32 * kt + 8 * qd]);
        B1B[kt] = ldcvt(&Wih1[gB * 64 + 32 * kt + 8 * qd]);
        B1A[kt + 2] = ldcvt(&Whh1[gA * 64 + 32 * kt + 8 * qd]);
        B1B[kt + 2] = ldcvt(&Whh1[gB * 64 + 32 * kt + 8 * qd]);
    }
    float b0A = bih0[gA] + bhh0[gA], b0B = bih0[gB] + bhh0[gB];
    float b1A = bih1[gA] + bhh1[gA], b1B = bih1[gB] + bhh1[gB];
    float w0A = Wih0[gA], w0B = Wih0[gB];

    float pwi = Wih0[d],       pbi = bih0[d]       + bhh0[d];
    float pwg = Wih0[128 + d], pbg = bih0[128 + d] + bhh0[128 + d];
    float pwo = Wih0[192 + d], pbo = bih0[192 + d] + bhh0[192 + d];

    float c0[2], c1[2];
    c0[0] = c0[1] = c1[0] = c1[1] = 0.f;

    __syncthreads();

    #pragma unroll
    for (int rl = 0; rl < 2; ++rl) {
        int rr = lo ? rl : 2 + rl;
        int m = 4 * qd + rr;
        float xv = xls[m];
        float gi = fmaf(pwi, xv, pbi);
        float gg = fmaf(pwg, xv, pbg);
        float go = fmaf(pwo, xv, pbo);
        float c = sigf(gi) * tanhf_(gg);
        c0[rl] = c;
        h0s[m * 72 + d] = (__bf16)(sigf(go) * tanhf_(c));
    }
    __syncthreads();

    for (int t = 0; t < TT; ++t) {
        bool last = (t == TT - 1);
        bf16x8 a0[2], a1[2];
        #pragma unroll
        for (int kt = 0; kt < 2; ++kt) {
            a0[kt] = *(bf16x8*)&h0s[l15 * 72 + 32 * kt + 8 * qd];
            a1[kt] = *(bf16x8*)&h1s[l15 * 72 + 32 * kt + 8 * qd];
        }
        f32x4 AA1, AB1, AA0, AB0;
        #pragma unroll
        for (int r = 0; r < 4; ++r) { AA1[r] = b1A; AB1[r] = b1B; }
        if (!last) {
            f32x4 xv = *(f32x4*)&xls[(t + 1) * 16 + 4 * qd];
            #pragma unroll
            for (int r = 0; r < 4; ++r) {
                AA0[r] = fmaf(w0A, xv[r], b0A);
                AB0[r] = fmaf(w0B, xv[r], b0B);
            }
        }
        #pragma unroll
        for (int kt = 0; kt < 2; ++kt) {
            AA1 = __builtin_amdgcn_mfma_f32_16x16x32_bf16(a0[kt], B1A[kt], AA1, 0, 0, 0);
            AB1 = __builtin_amdgcn_mfma_f32_16x16x32_bf16(a0[kt], B1B[kt], AB1, 0, 0, 0);
            AA1 = __builtin_amdgcn_mfma_f32_16x16x32_bf16(a1[kt], B1A[kt + 2], AA1, 0, 0, 0);
            AB1 = __builtin_amdgcn_mfma_f32_16x16x32_bf16(a1[kt], B1B[kt + 2], AB1, 0, 0, 0);
        }
        if (!last) {
            #pragma unroll
            for (int kt = 0; kt < 2; ++kt) {
                AA0 = __builtin_amdgcn_mfma_f32_16x16x32_bf16(a0[kt], B0A[kt], AA0, 0, 0, 0);
                AB0 = __builtin_amdgcn_mfma_f32_16x16x32_bf16(a0[kt], B0B[kt], AB0, 0, 0, 0);
            }
        }
        __syncthreads();

        {
            float shA0 = __shfl_xor(lo ? AA1[2] : AA1[0], 8);
            float shA1 = __shfl_xor(lo ? AA1[3] : AA1[1], 8);
            float shB0 = __shfl_xor(lo ? AB1[2] : AB1[0], 8);
            float shB1 = __shfl_xor(lo ? AB1[3] : AB1[1], 8);
            #pragma unroll
            for (int rl = 0; rl < 2; ++rl) {
                int rr = lo ? rl : 2 + rl;
                float ownA = AA1[rr], ownB = AB1[rr];
                float shA = rl ? shA1 : shA0, shB = rl ? shB1 : shB0;
                float gi = lo ? ownA : shA;
                float gf = lo ? shA : ownA;
                float gg = lo ? ownB : shB;
                float go = lo ? shB : ownB;
                float c = sigf(gf) * c1[rl] + sigf(gi) * tanhf_(gg);
                c1[rl] = c;
                float hv = sigf(go) * tanhf_(c);
                int m = 4 * qd + rr;
                h1s[m * 72 + d] = (__bf16)hv;
            }
        }
        if (!last) {
            float shA0 = __shfl_xor(lo ? AA0[2] : AA0[0], 8);
            float shA1 = __shfl_xor(lo ? AA0[3] : AA0[1], 8);
            float shB0 = __shfl_xor(lo ? AB0[2] : AB0[0], 8);
            float shB1 = __shfl_xor(lo ? AB0[3] : AB0[1], 8);
            #pragma unroll
            for (int rl = 0; rl < 2; ++rl) {
                int rr = lo ? rl : 2 + rl;
                float ownA = AA0[rr], ownB = AB0[rr];
                float shA = rl ? shA1 : shA0, shB = rl ? shB1 : shB0;
                float gi = lo ? ownA : shA;
                float gf = lo ? shA : ownA;
                float gg = lo ? ownB : shB;
                float go = lo ? shB : ownB;
                float c = sigf(gf) * c0[rl] + sigf(gi) * tanhf_(gg);
                c0[rl] = c;
                int m = 4 * qd + rr;
                h0s[m * 72 + d] = (__bf16)(sigf(go) * tanhf_(c));
            }
        }
        __syncthreads();
    }

    // fused prep0
    int s0 = blockIdx.x * 16;
    if (w < 4) {
        int mt = w;
        bf16x8 Bf0 = *(bf16x8*)&h1s[l15 * 72 + 8 * qd];
        bf16x8 Bf1 = *(bf16x8*)&h1s[l15 * 72 + 32 + 8 * qd];
        bf16x8 A0 = ldcvt(&gW[(mt * 16 + l15) * 64 + 8 * qd]);
        bf16x8 A1 = ldcvt(&gW[(mt * 16 + l15) * 64 + 32 + 8 * qd]);
        f32x4 a = {0.f, 0.f, 0.f, 0.f};
        a = __builtin_amdgcn_mfma_f32_16x16x32_bf16(A0, Bf0, a, 0, 0, 0);
        a = __builtin_amdgcn_mfma_f32_16x16x32_bf16(A1, Bf1, a, 0, 0, 0);
        float ts = 0.f, td = 0.f;
        #pragma unroll
        for (int r = 0; r < 4; ++r) {
            int dd = mt * 16 + qd * 4 + r;
            ts = fmaf(a[r], avs[dd], ts);
            td = fmaf(a[r], avs[64 + dd], td);
            hp_t[dd * 24 + l15] = (__bf16)a[r];
        }
        ts += __shfl_xor(ts, 16); ts += __shfl_xor(ts, 32);
        td += __shfl_xor(td, 16); td += __shfl_xor(td, 32);
        if (qd == 0) {
            int s = s0 + l15, b = s / NNODE, n = s - b * NNODE;
            esT[(b * 4 + mt) * NPAD + n] = ts;
            edT[(b * 4 + mt) * NPAD + n] = td;
        }
    }
    __syncthreads();
    if (tid < 256) {
        int dim = tid >> 2, seg = tid & 3;
        int b0 = s0 / NNODE, b1 = (s0 + 15) / NNODE;
        if (b0 == b1) {
            int n0 = s0 - b0 * NNODE;
            bf16x4 v = *(bf16x4*)&hp_t[dim * 24 + seg * 4];
            *(bf16x4*)&hpT[((b0 << 6) + dim) * NPAD + n0 + seg * 4] = v;
        } else {
            #pragma unroll
            for (int u = 0; u < 4; ++u) {
                int ss = s0 + seg * 4 + u;
                int b = ss / NNODE, n = ss - b * NNODE;
                hpT[((b << 6) + dim) * NPAD + n] = hp_t[dim * 24 + seg * 4 + u];
            }
        }
    }
}

// ---------------------------------------------------------------------------
// Kernel B: GAT0 aggregation + fused GAT1 projection.
// Block = 16 nodes x 4 waves (one head each); grid = 8 x 94 = 752.
// ed rows (all 4 heads) + mask rows staged in LDS (mask transposed ->
// conflict-free). Inner loop: only 1 global stream (Brow, coalesced).
// ---------------------------------------------------------------------------
__global__ __launch_bounds__(256, 1) void gat_mid(
    const __bf16* __restrict__ hpT, const float* __restrict__ esT,
    const float* __restrict__ edT, const unsigned int* __restrict__ mask,
    const float* __restrict__ gW, const float* __restrict__ asrc,
    const float* __restrict__ adst,
    __bf16* __restrict__ hpT1, float* __restrict__ esT1, float* __restrict__ edT1)
{
    __shared__ __align__(16) float edls[4 * NPAD];   // 24 KB
    __shared__ unsigned int mskls[48 * 16];          // 3 KB [chunk][i]
    __shared__ float Ss[4][16];
    __shared__ float hbuf[16 * 72];                  // 4.5 KB [node][dim]
    __shared__ float avs[128];
    __shared__ __align__(16) __bf16 hp1_t[64 * 24];  // 3 KB [dim][node]

    int tid  = threadIdx.x;
    int wv   = tid >> 6;        // head
    int lane = tid & 63;
    int l15  = lane & 15;
    int qd   = lane >> 4;
    int b    = blockIdx.x / 94;
    int i0   = (blockIdx.x % 94) * 16;

    if (tid < 64)       avs[tid] = asrc[tid] * LOG2E;
    else if (tid < 128) avs[tid] = adst[tid - 64] * LOG2E;
    {
        const float4* src = (const float4*)(edT + (b * 4) * NPAD);
        float4* dst = (float4*)edls;
        for (int u = tid; u < NPAD; u += 256) dst[u] = src[u];
    }
    for (int u = tid; u < 16 * 48; u += 256) {
        int il = u / 48, c = u - il * 48;
        mskls[c * 16 + il] = mask[(i0 + il) * 48 + c];
    }
    __syncthreads();

    const __bf16* Brow = hpT + (((b << 6) + (wv << 4) + l15) * NPAD);
    const float* edrow = edls + wv * NPAD;
    float esv = esT[(b * 4 + wv) * NPAD + i0 + l15];

    f32x4 acc = {0.f, 0.f, 0.f, 0.f};
    float S = 0.f;

    for (int jt = 0; jt < 12; ++jt) {
        #pragma unroll
        for (int kt = 0; kt < 4; ++kt) {
            int jk = jt * 128 + kt * 32 + qd * 8;
            float4 e0 = *(const float4*)&edrow[jk];
            float4 e1 = *(const float4*)&edrow[jk + 4];
            unsigned int mb = (mskls[(jt * 4 + kt) * 16 + l15] >> (qd * 8)) & 0xffu;
            float ej[8] = {e0.x, e0.y, e0.z, e0.w, e1.x, e1.y, e1.z, e1.w};
            bf16x8 A;
            #pragma unroll
            for (int jj = 0; jj < 8; ++jj) {
                float e = esv + ej[jj];
                e = fmaxf(e, 0.2f * e);
                float p = ((mb >> jj) & 1u) ? exp2f_(e) : 0.f;
                S += p;
                A[jj] = (__bf16)p;
            }
            bf16x8 B = *(const bf16x8*)&Brow[jk];
            acc = __builtin_amdgcn_mfma_f32_16x16x32_bf16(A, B, acc, 0, 0, 0);
        }
    }

    S += __shfl_xor(S, 16);
    S += __shfl_xor(S, 32);
    if (qd == 0) Ss[wv][l15] = S;
    __syncthreads();

    #pragma unroll
    for (int r = 0; r < 4; ++r) {
        float rs = rcpf(Ss[wv][qd * 4 + r]);
        hbuf[(qd * 4 + r) * 72 + (wv << 4) + l15] = fmaxf(acc[r] * rs, 0.f);
    }
    __syncthreads();

    // fused prep1: wave wv = dim-tile mt
    {
        int mt = wv;
        bf16x8 Bf0 = ldcvt(&hbuf[l15 * 72 + 8 * qd]);
        bf16x8 Bf1 = ldcvt(&hbuf[l15 * 72 + 32 + 8 * qd]);
        bf16x8 A0 = ldcvt(&gW[(mt * 16 + l15) * 64 + 8 * qd]);
        bf16x8 A1 = ldcvt(&gW[(mt * 16 + l15) * 64 + 32 + 8 * qd]);
        f32x4 a = {0.f, 0.f, 0.f, 0.f};
        a = __builtin_amdgcn_mfma_f32_16x16x32_bf16(A0, Bf0, a, 0, 0, 0);
        a = __builtin_amdgcn_mfma_f32_16x16x32_bf16(A1, Bf1, a, 0, 0, 0);
        float ts = 0.f, td = 0.f;
        #pragma unroll
        for (int r = 0; r < 4; ++r) {
            int dd = mt * 16 + qd * 4 + r;
            ts = fmaf(a[r], avs[dd], ts);
            td = fmaf(a[r], avs[64 + dd], td);
            hp1_t[dd * 24 + l15] = (__bf16)a[r];
        }
        ts += __shfl_xor(ts, 16); ts += __shfl_xor(ts, 32);
        td += __shfl_xor(td, 16); td += __shfl_xor(td, 32);
        if (qd == 0) {
            int n = i0 + l15;
            esT1[(b * 4 + mt) * NPAD + n] = ts;
            edT1[(b * 4 + mt) * NPAD + n] = td;
        }
    }
    __syncthreads();
    {
        int dim = tid >> 2, seg = tid & 3;
        bf16x4 v = *(bf16x4*)&hp1_t[dim * 24 + seg * 4];
        *(bf16x4*)&hpT1[((b << 6) + dim) * NPAD + i0 + seg * 4] = v;
    }
}

// ---------------------------------------------------------------------------
// Kernel C: GAT1 aggregation + fused linear head -> d_out.
// Same 16-node / 4-wave structure as kernel B.
// ---------------------------------------------------------------------------
__global__ __launch_bounds__(256, 1) void gat_fin(
    const __bf16* __restrict__ hpT, const float* __restrict__ esT,
    const float* __restrict__ edT, const unsigned int* __restrict__ mask,
    const float* __restrict__ oW, const float* __restrict__ ob,
    float* __restrict__ outp)
{
    __shared__ __align__(16) float edls[4 * NPAD];   // 24 KB
    __shared__ unsigned int mskls[48 * 16];          // 3 KB
    __shared__ float Ss[4][16];
    __shared__ float hbuf[16 * 72];
    __shared__ float oWs[192];
    __shared__ float obs[3];

    int tid  = threadIdx.x;
    int wv   = tid >> 6;
    int lane = tid & 63;
    int l15  = lane & 15;
    int qd   = lane >> 4;
    int b    = blockIdx.x / 94;
    int i0   = (blockIdx.x % 94) * 16;

    if (tid < 192) oWs[tid] = oW[tid];
    if (tid < 3)   obs[tid] = ob[tid];
    {
        const float4* src = (const float4*)(edT + (b * 4) * NPAD);
        float4* dst = (float4*)edls;
        for (int u = tid; u < NPAD; u += 256) dst[u] = src[u];
    }
    for (int u = tid; u < 16 * 48; u += 256) {
        int il = u / 48, c = u - il * 48;
        mskls[c * 16 + il] = mask[(i0 + il) * 48 + c];
    }
    __syncthreads();

    const __bf16* Brow = hpT + (((b << 6) + (wv << 4) + l15) * NPAD);
    const float* edrow = edls + wv * NPAD;
    float esv = esT[(b * 4 + wv) * NPAD + i0 + l15];

    f32x4 acc = {0.f, 0.f, 0.f, 0.f};
    float S = 0.f;

    for (int jt = 0; jt < 12; ++jt) {
        #pragma unroll
        for (int kt = 0; kt < 4; ++kt) {
            int jk = jt * 128 + kt * 32 + qd * 8;
            float4 e0 = *(const float4*)&edrow[jk];
            float4 e1 = *(const float4*)&edrow[jk + 4];
            unsigned int mb = (mskls[(jt * 4 + kt) * 16 + l15] >> (qd * 8)) & 0xffu;
            float ej[8] = {e0.x, e0.y, e0.z, e0.w, e1.x, e1.y, e1.z, e1.w};
            bf16x8 A;
            #pragma unroll
            for (int jj = 0; jj < 8; ++jj) {
                float e = esv + ej[jj];
                e = fmaxf(e, 0.2f * e);
                float p = ((mb >> jj) & 1u) ? exp2f_(e) : 0.f;
                S += p;
                A[jj] = (__bf16)p;
            }
            bf16x8 B = *(const bf16x8*)&Brow[jk];
            acc = __builtin_amdgcn_mfma_f32_16x16x32_bf16(A, B, acc, 0, 0, 0);
        }
    }

    S += __shfl_xor(S, 16);
    S += __shfl_xor(S, 32);
    if (qd == 0) Ss[wv][l15] = S;
    __syncthreads();

    #pragma unroll
    for (int r = 0; r < 4; ++r) {
        float rs = rcpf(Ss[wv][qd * 4 + r]);
        hbuf[(qd * 4 + r) * 72 + (wv << 4) + l15] = fmaxf(acc[r] * rs, 0.f);
    }
    __syncthreads();

    if (tid < 192) {
        int idx = tid >> 2, ks = tid & 3;
        int nl = idx & 15, o = idx >> 4;
        if (i0 + nl < NNODE) {
            const float* hb = &hbuf[nl * 72 + ks * 16];
            float a = 0.f;
            #pragma unroll
            for (int kk = 0; kk < 16; ++kk)
                a = fmaf(hb[kk], oWs[o * 64 + ks * 16 + kk], a);
            a += __shfl_xor(a, 1);
            a += __shfl_xor(a, 2);
            if (ks == 0)
                outp[(long)b * 3 * NNODE + o * NNODE + i0 + nl] = a + obs[o];
        }
    }
}

// ---------------------------------------------------------------------------
extern "C" void kernel_launch(void* const* d_in, const int* in_sizes, int n_in,
                              void* d_out, int out_size, void* d_ws, size_t ws_size,
                              hipStream_t stream) {
    const float* x    = (const float*)d_in[0];
    const int*   adj  = (const int*)d_in[1];
    const float* Wih0 = (const float*)d_in[2];
    const float* Whh0 = (const float*)d_in[3];
    const float* bih0 = (const float*)d_in[4];
    const float* bhh0 = (const float*)d_in[5];
    const float* Wih1 = (const float*)d_in[6];
    const float* Whh1 = (const float*)d_in[7];
    const float* bih1 = (const float*)d_in[8];
    const float* bhh1 = (const float*)d_in[9];
    const float* g0W  = (const float*)d_in[10];
    const float* g0s  = (const float*)d_in[11];
    const float* g0d  = (const float*)d_in[12];
    const float* g1W  = (const float*)d_in[13];
    const float* g1s  = (const float*)d_in[14];
    const float* g1d  = (const float*)d_in[15];
    const float* oW   = (const float*)d_in[16];
    const float* ob   = (const float*)d_in[17];

    float* ws = (float*)d_ws;
    float*        esT0  = ws;                              // 49152
    float*        edT0  = ws + 49152;                      // 49152
    float*        esT1  = ws + 98304;                      // 49152
    float*        edT1  = ws + 147456;                     // 49152
    __bf16*       hpT0  = (__bf16*)(ws + 196608);          // 512*1536 bf16
    __bf16*       hpT1  = (__bf16*)(ws + 589824);          // 512*1536 bf16
    unsigned int* maskp = (unsigned int*)(ws + 983040);    // 72192 u32

    lstm_mask_prep<<<1032, 512, 0, stream>>>(x, Wih0, Whh0, bih0, bhh0,
                                             Wih1, Whh1, bih1, bhh1,
                                             adj, maskp, g0W, g0s, g0d,
                                             hpT0, esT0, edT0);
    gat_mid<<<752, 256, 0, stream>>>(hpT0, esT0, edT0, maskp,
                                     g1W, g1s, g1d, hpT1, esT1, edT1);
    gat_fin<<<752, 256, 0, stream>>>(hpT1, esT1, edT1, maskp,
                                     oW, ob, (float*)d_out);
}